// Round 3
// baseline (358.104 us; speedup 1.0000x reference)
//
#include <hip/hip_runtime.h>
#include <stdint.h>

#define NN 100000
#define FF 128
#define NB 391              // ceil(NN/256) buckets of 256 nodes

typedef __bf16 bf16x8 __attribute__((ext_vector_type(8)));
typedef float f32x4 __attribute__((ext_vector_type(4)));

__device__ __forceinline__ unsigned short f2bf(float f) {
    unsigned int u = __float_as_uint(f);
    u += 0x7FFF + ((u >> 16) & 1);          // round-to-nearest-even
    return (unsigned short)(u >> 16);
}
__device__ __forceinline__ float bf2f(unsigned short b) {
    return __uint_as_float(((unsigned int)b) << 16);
}

__device__ __forceinline__ int edge_at(const void* ei, int idx, int is64) {
    if (is64) return (int)((const long long*)ei)[idx];
    return ((const int*)ei)[idx];
}

// ---------- init: zero bucket counters + edge dtype detect ----------
__global__ void init_kernel(const unsigned int* ei, int* flag, int* bcnt) {
    __shared__ int any;
    int t = threadIdx.x;
    if (t == 0) any = 0;
    for (int i = t; i < NB; i += 512) bcnt[i] = 0;
    __syncthreads();
    unsigned int v = ei[2 * t + 1];
    if (v != 0u) atomicOr(&any, 1);
    __syncthreads();
    if (t == 0) *flag = (any ? 0 : 1);  // 1 => int64
}

// ---------- fused: bucket histogram (blocks 0-255) + prep (blocks 256+) ----------
__global__ void bcount_prep_kernel(const void* ei, const int* flag, int* bcnt, int E,
                                   const float* __restrict__ x, unsigned short* __restrict__ xb,
                                   const float* Wl0, const float* Wr0,
                                   const float* Wl1, const float* Wr1,
                                   const float* Wl2, const float* Wr2,
                                   unsigned short* __restrict__ whi) {
    if (blockIdx.x < 256) {
        __shared__ int h[NB];
        for (int i = threadIdx.x; i < NB; i += 256) h[i] = 0;
        __syncthreads();
        int is64 = *flag;
        int stride = 256 * 256;
        for (int e = blockIdx.x * 256 + threadIdx.x; e < E; e += stride)
            atomicAdd(&h[edge_at(ei, E + e, is64) >> 8], 1);
        __syncthreads();
        for (int i = threadIdx.x; i < NB; i += 256) {
            int v = h[i];
            if (v) atomicAdd(&bcnt[i], v);
        }
    } else {
        int gid = (blockIdx.x - 256) * 256 + threadIdx.x;
        int gstride = (gridDim.x - 256) * 256;
        const int PC = NN * FF / 8;
        for (int i = gid; i < PC; i += gstride) {
            float4 a = ((const float4*)x)[i * 2];
            float4 b = ((const float4*)x)[i * 2 + 1];
            ushort4 p0 = make_ushort4(f2bf(a.x), f2bf(a.y), f2bf(a.z), f2bf(a.w));
            ushort4 p1 = make_ushort4(f2bf(b.x), f2bf(b.y), f2bf(b.z), f2bf(b.w));
            ((ushort4*)xb)[i * 2] = p0;
            ((ushort4*)xb)[i * 2 + 1] = p1;
        }
        const int WT = 3 * 256 * FF;
        for (int i = gid; i < WT; i += gstride) {
            int l = i >> 15;                 // / (256*128)
            int rem = i & 32767;
            int n = rem >> 7;
            int k = rem & 127;
            const float* Wl = l == 0 ? Wl0 : (l == 1 ? Wl1 : Wl2);
            const float* Wr = l == 0 ? Wr0 : (l == 1 ? Wr1 : Wr2);
            float v = (n < FF) ? Wl[k * FF + n] : Wr[k * FF + (n - FF)];
            whi[i] = f2bf(v);
        }
    }
}

__global__ void bscan_kernel(const int* bcnt, int* bbase, int* bcursor,
                             int* rowptr, int E) {
    __shared__ int s[512];
    int t = threadIdx.x;
    int v = (t < NB) ? bcnt[t] : 0;
    s[t] = v;
    __syncthreads();
    for (int off = 1; off < 512; off <<= 1) {
        int u = (t >= off) ? s[t - off] : 0;
        __syncthreads();
        s[t] += u;
        __syncthreads();
    }
    if (t <= NB) {
        int excl = (t == 0) ? 0 : s[t - 1];
        bbase[t] = excl;                 // bbase[NB] == E
        if (t < NB) bcursor[t] = excl;
    }
    if (t == 0) rowptr[NN] = E;
}

// each block reserves per-bucket runs, writes packed (src<<8 | dstLocal)
__global__ void bscatter_kernel(const void* ei, const int* flag, int* bcursor,
                                unsigned int* packed, int E, int CH) {
    __shared__ int cnt[NB];
    __shared__ int base[NB];
    int t = threadIdx.x;
    for (int i = t; i < NB; i += 256) cnt[i] = 0;
    __syncthreads();
    int is64 = *flag;
    int beg = blockIdx.x * CH;
    int end = min(E, beg + CH);
    for (int e = beg + t; e < end; e += 256)
        atomicAdd(&cnt[edge_at(ei, E + e, is64) >> 8], 1);
    __syncthreads();
    for (int i = t; i < NB; i += 256) {
        int c = cnt[i];
        base[i] = c ? atomicAdd(&bcursor[i], c) : 0;
    }
    __syncthreads();
    for (int i = t; i < NB; i += 256) cnt[i] = 0;
    __syncthreads();
    for (int e = beg + t; e < end; e += 256) {
        int sV = edge_at(ei, e, is64);
        int d  = edge_at(ei, E + e, is64);
        int b = d >> 8;
        int pos = base[b] + atomicAdd(&cnt[b], 1);
        packed[pos] = ((unsigned int)sV << 8) | (unsigned int)(d & 255);
    }
}

// one block per bucket: local count+scan -> rowptr, local cursor scatter -> col
__global__ void bfill_kernel(const unsigned int* __restrict__ packed,
                             const int* __restrict__ bbase,
                             int* __restrict__ rowptr, int* __restrict__ col) {
    __shared__ int cnt[256];
    __shared__ int scn[256];
    __shared__ int exc[256];
    int t = threadIdx.x;
    int b = blockIdx.x;
    int ebeg = bbase[b], eend = bbase[b + 1];
    cnt[t] = 0;
    __syncthreads();
    for (int e = ebeg + t; e < eend; e += 256)
        atomicAdd(&cnt[packed[e] & 255], 1);
    __syncthreads();
    int v = cnt[t];
    scn[t] = v;
    __syncthreads();
    for (int off = 1; off < 256; off <<= 1) {
        int u = (t >= off) ? scn[t - off] : 0;
        __syncthreads();
        scn[t] += u;
        __syncthreads();
    }
    int excl = scn[t] - v;
    exc[t] = excl;
    int node = b * 256 + t;
    if (node < NN) rowptr[node] = ebeg + excl;
    cnt[t] = 0;                           // reuse as cursor
    __syncthreads();
    for (int e = ebeg + t; e < eend; e += 256) {
        unsigned int p = packed[e];
        int l = p & 255;
        int pos = ebeg + exc[l] + atomicAdd(&cnt[l], 1);
        col[pos] = (int)(p >> 8);
    }
}

// ---------- aggregation: m_i = mean_{j in N(i)} h_j  (bf16 in, bf16 out) ----------
// One wave per dst. Pair-gather: lanes 0-31 read row c[2p], lanes 32-63 read
// row c[2p+1] -> 64 lanes x 8B = TWO full 256B rows per dwordx2 instruction.
// Row-index select off-VALU via ds_bpermute on the batch colv; gather address
// is a single 32-bit voffset (v_lshl_add_u32) against the SGPR table base.
// Depth-4 pair pipeline = 8 edges in flight. Odd-degree tail masks the
// invalid high half with a precomputed lane mask under a uniform branch.
__global__ void aggregate_kernel(const unsigned short* __restrict__ h,
                                 const int* __restrict__ rowptr,
                                 const int* __restrict__ col,
                                 unsigned short* __restrict__ m) {
    int gw = (int)((blockIdx.x * blockDim.x + threadIdx.x) >> 6);
    gw = __builtin_amdgcn_readfirstlane(gw);
    if (gw >= NN) return;
    const int lane = (int)(threadIdx.x & 63);
    const int half = lane >> 5;                 // 0 = low rows, 1 = high rows
    const int loff = (lane & 31) * 8;           // byte offset within a 256B row
    const int pidx = half * 4;                  // bpermute byte-index base
    const unsigned lomask = half ? 0u : 0xFFFFFFFFu;

    int beg = __builtin_amdgcn_readfirstlane(rowptr[gw]);
    int end = __builtin_amdgcn_readfirstlane(rowptr[gw + 1]);
    int deg = end - beg;
    float a0 = 0.f, a1 = 0.f, a2 = 0.f, a3 = 0.f;

    int done = 0;
    while (done < deg) {
        int batch = min(deg - done, 64);
        int np = (batch + 1) >> 1;              // pairs this batch
        int colv = __builtin_nontemporal_load(&col[beg + min(done + lane, deg - 1)]);

        auto LD = [&](int p) -> uint2 {
            int bidx = p * 8 + pidx;                            // lane 2p+half
            int c = __builtin_amdgcn_ds_bpermute(bidx, colv);
            unsigned off = ((unsigned)c << 8) + (unsigned)loff; // table < 4GB
            uint2 v = *(const uint2*)((const char*)h + off);
            if (2 * p + 1 >= batch) { v.x &= lomask; v.y &= lomask; }  // odd tail
            return v;
        };
        auto ACC = [&](uint2 v) {
            a0 += __uint_as_float(v.x << 16);
            a1 += __uint_as_float(v.x & 0xffff0000u);
            a2 += __uint_as_float(v.y << 16);
            a3 += __uint_as_float(v.y & 0xffff0000u);
        };

        uint2 u0 = make_uint2(0, 0), u1 = make_uint2(0, 0);
        uint2 u2 = make_uint2(0, 0), u3 = make_uint2(0, 0);
        u0 = LD(0);
        if (1 < np) u1 = LD(1);
        if (2 < np) u2 = LD(2);
        if (3 < np) u3 = LD(3);
        for (int p = 0; p < np; p += 4) {
            uint2 n0 = make_uint2(0, 0), n1 = make_uint2(0, 0);
            uint2 n2 = make_uint2(0, 0), n3 = make_uint2(0, 0);
            if (p + 4 < np) n0 = LD(p + 4);
            if (p + 5 < np) n1 = LD(p + 5);
            if (p + 6 < np) n2 = LD(p + 6);
            if (p + 7 < np) n3 = LD(p + 7);
            ACC(u0); ACC(u1); ACC(u2); ACC(u3);
            u0 = n0; u1 = n1; u2 = n2; u3 = n3;
        }
        done += batch;
    }

    // fold the two halves (even edges in lanes 0-31, odd edges in lanes 32-63)
    a0 += __shfl_xor(a0, 32);
    a1 += __shfl_xor(a1, 32);
    a2 += __shfl_xor(a2, 32);
    a3 += __shfl_xor(a3, 32);

    if (lane < 32) {
        float r = deg > 0 ? 1.f / (float)deg : 0.f;
        unsigned long long pk =
            (unsigned long long)((unsigned)f2bf(a0 * r) | ((unsigned)f2bf(a1 * r) << 16)) |
            ((unsigned long long)((unsigned)f2bf(a2 * r) | ((unsigned)f2bf(a3 * r) << 16)) << 32);
        __builtin_nontemporal_store(pk,
            (unsigned long long*)((char*)m + ((size_t)gw << 8) + loff));
    }
}

// ---------- GEMM: out = m@Wl + h@Wr + bl  (bf16 W direct from L2) ----------
// 256 threads, M-tile 64 x N 128, 4 waves n-split (wid*32), acc[4][2].
// Only M/H staged in LDS (10 KB); W fragments loaded per-lane from global (L2-hot).
// Swapped mfma -> C^T frags -> swizzled LDS C-tile (16 KB) -> coalesced stores.
// WMODE 0: bf16 + relu. WMODE 1: fp32, no relu (two 32-row rounds).
template <int WMODE>
__global__ __launch_bounds__(256, 6) void gemm_mfma_kernel(
        const unsigned short* __restrict__ mb,    // [NN][128] bf16 mean
        const unsigned short* __restrict__ hb,    // [NN][128] bf16 root
        const unsigned short* __restrict__ w2,    // [256][128]: rows 0-127 Wl, 128-255 Wr
        const float* __restrict__ bl,
        void* __restrict__ outp) {
    __shared__ __align__(16) char smem[16384];
    // stage: Mt 0..5120, Ht 5120..10240 ; row stride 80B

    const int t = threadIdx.x;
    const int lane = t & 63;
    const int wid = t >> 6;
    const int m0 = blockIdx.x * 64;
    const int n0w = wid * 32;

    f32x4 acc[4][2];
    #pragma unroll
    for (int mr = 0; mr < 4; ++mr)
        #pragma unroll
        for (int nr = 0; nr < 2; ++nr) acc[mr][nr] = (f32x4){0.f, 0.f, 0.f, 0.f};

    const int srow = t >> 2;            // 0..63
    const int sk8 = (t & 3) * 8;
    const int arow = lane & 15;
    const int kg = (lane >> 4) * 8;     // element offset within 32-k chunk

    uint4 pfM, pfH;
    auto issueA = [&](int kc) {
        int gr = m0 + srow; if (gr >= NN) gr = NN - 1;
        size_t ga = (size_t)gr * FF + kc * 32 + sk8;
        pfM = *(const uint4*)(mb + ga);
        pfH = *(const uint4*)(hb + ga);
    };

    issueA(0);
    for (int kc = 0; kc < 4; ++kc) {
        __syncthreads();
        *(uint4*)(smem +        srow * 80 + sk8 * 2) = pfM;
        *(uint4*)(smem + 5120 + srow * 80 + sk8 * 2) = pfH;
        if (kc < 3) issueA(kc + 1);
        __syncthreads();

        // W fragments direct from global (L2-resident, broadcast across blocks)
        bf16x8 wfrag[4];
        #pragma unroll
        for (int nr = 0; nr < 2; ++nr) {
            int n = n0w + nr * 16 + arow;
            wfrag[nr * 2 + 0] = *(const bf16x8*)(w2 + (size_t)n * FF + kc * 32 + kg);
            wfrag[nr * 2 + 1] = *(const bf16x8*)(w2 + (size_t)(128 + n) * FF + kc * 32 + kg);
        }
        const int kg2 = (lane >> 4) * 16;   // byte offset of 8 bf16
        #pragma unroll
        for (int mr = 0; mr < 4; ++mr) {
            int row = mr * 16 + arow;
            bf16x8 a_m = *(const bf16x8*)(smem +        row * 80 + kg2);
            bf16x8 a_h = *(const bf16x8*)(smem + 5120 + row * 80 + kg2);
            #pragma unroll
            for (int nr = 0; nr < 2; ++nr) {
                acc[mr][nr] = __builtin_amdgcn_mfma_f32_16x16x32_bf16(wfrag[nr * 2 + 0], a_m, acc[mr][nr], 0, 0, 0);
                acc[mr][nr] = __builtin_amdgcn_mfma_f32_16x16x32_bf16(wfrag[nr * 2 + 1], a_h, acc[mr][nr], 0, 0, 0);
            }
        }
    }

    // ---- epilogue via swizzled LDS C-tile ----
    const int nodeL = lane & 15;
    const int rg4 = (lane >> 4) * 4;
    if (WMODE == 0) {
        __syncthreads();
        #pragma unroll
        for (int nr = 0; nr < 2; ++nr) {
            int n = n0w + nr * 16 + rg4;
            float4 bias = *(const float4*)(bl + n);
            int g = n >> 2;
            #pragma unroll
            for (int mr = 0; mr < 4; ++mr) {
                int row = mr * 16 + nodeL;             // 0..63
                f32x4 a = acc[mr][nr];
                float o0 = fmaxf(a[0] + bias.x, 0.f), o1 = fmaxf(a[1] + bias.y, 0.f);
                float o2 = fmaxf(a[2] + bias.z, 0.f), o3 = fmaxf(a[3] + bias.w, 0.f);
                ushort4 p = make_ushort4(f2bf(o0), f2bf(o1), f2bf(o2), f2bf(o3));
                *(ushort4*)(smem + row * 256 + ((g ^ ((row & 7) << 2)) << 3)) = p;
            }
        }
        __syncthreads();
        unsigned short* hout = (unsigned short*)outp;
        #pragma unroll
        for (int it = 0; it < 8; ++it) {
            int idx = t + it * 256;
            int row = idx >> 5;                        // 0..63
            int g = idx & 31;
            int node = m0 + row;
            if (node < NN) {
                ushort4 v = *(const ushort4*)(smem + row * 256 + ((g ^ ((row & 7) << 2)) << 3));
                *(ushort4*)(hout + (size_t)node * FF + g * 4) = v;
            }
        }
    } else {
        float* fout = (float*)outp;
        #pragma unroll
        for (int r = 0; r < 2; ++r) {
            __syncthreads();
            #pragma unroll
            for (int nr = 0; nr < 2; ++nr) {
                int n = n0w + nr * 16 + rg4;
                float4 bias = *(const float4*)(bl + n);
                int g = n >> 2;
                #pragma unroll
                for (int mr = 2 * r; mr < 2 * r + 2; ++mr) {
                    int lrow = mr * 16 + nodeL - 32 * r;   // 0..31
                    f32x4 a = acc[mr][nr];
                    float4 p = make_float4(a[0] + bias.x, a[1] + bias.y,
                                           a[2] + bias.z, a[3] + bias.w);
                    *(float4*)(smem + lrow * 512 + ((g ^ (lrow & 7)) << 4)) = p;
                }
            }
            __syncthreads();
            #pragma unroll
            for (int it = 0; it < 4; ++it) {
                int idx = t + it * 256;
                int lrow = idx >> 5;                   // 0..31
                int g = idx & 31;
                int node = m0 + 32 * r + lrow;
                if (node < NN) {
                    float4 v = *(const float4*)(smem + lrow * 512 + ((g ^ (lrow & 7)) << 4));
                    *(float4*)(fout + (size_t)node * FF + g * 4) = v;
                }
            }
        }
    }
}

extern "C" void kernel_launch(void* const* d_in, const int* in_sizes, int n_in,
                              void* d_out, int out_size, void* d_ws, size_t ws_size,
                              hipStream_t stream) {
    const float* x   = (const float*)d_in[0];
    const void*  ei  = d_in[1];
    const float* Wl0 = (const float*)d_in[2];
    const float* bl0 = (const float*)d_in[3];
    const float* Wr0 = (const float*)d_in[4];
    const float* Wl1 = (const float*)d_in[5];
    const float* bl1 = (const float*)d_in[6];
    const float* Wr1 = (const float*)d_in[7];
    const float* Wl2 = (const float*)d_in[8];
    const float* bl2 = (const float*)d_in[9];
    const float* Wr2 = (const float*)d_in[10];
    float* out = (float*)d_out;
    const int E = in_sizes[1] / 2;

    char* w = (char*)d_ws;
    size_t off = 0;
    auto alloc = [&](size_t bytes) {
        void* p = w + off;
        off += (bytes + 511) & ~(size_t)511;
        return p;
    };
    int*            flag    = (int*)alloc(4);
    int*            bcnt    = (int*)alloc(sizeof(int) * NB);
    int*            bbase   = (int*)alloc(sizeof(int) * (NB + 1));
    int*            bcursor = (int*)alloc(sizeof(int) * NB);
    int*            rowptr  = (int*)alloc(sizeof(int) * (NN + 1));
    unsigned int*   packed  = (unsigned int*)alloc(sizeof(int) * E);
    int*            col     = (int*)alloc(sizeof(int) * E);
    unsigned short* whi     = (unsigned short*)alloc(sizeof(short) * 3 * 256 * FF);
    unsigned short* xb      = (unsigned short*)alloc(sizeof(short) * (size_t)NN * FF);
    unsigned short* mbuf    = (unsigned short*)alloc(sizeof(short) * (size_t)NN * FF);
    unsigned short* hA      = (unsigned short*)alloc(sizeof(short) * (size_t)NN * FF);
    unsigned short* hB      = xb;   // xb dead after layer-0 gemm; reuse

    // ---- CSR build (bucketed) + prep fused into histogram pass ----
    init_kernel<<<1, 512, 0, stream>>>((const unsigned int*)ei, flag, bcnt);
    bcount_prep_kernel<<<1280, 256, 0, stream>>>(ei, flag, bcnt, E,
                                                 x, xb, Wl0, Wr0, Wl1, Wr1, Wl2, Wr2, whi);
    bscan_kernel<<<1, 512, 0, stream>>>(bcnt, bbase, bcursor, rowptr, E);
    int CH = (E + 255) / 256;
    bscatter_kernel<<<256, 256, 0, stream>>>(ei, flag, bcursor, packed, E, CH);
    bfill_kernel<<<NB, 256, 0, stream>>>(packed, bbase, rowptr, col);

    int gb = (NN + 63) / 64;
    int ab = (NN * 64 + 255) / 256;

    // layer 0: m = mean(xb); h1 = relu(m@Wl0 + xb@Wr0 + bl0)
    aggregate_kernel<<<ab, 256, 0, stream>>>(xb, rowptr, col, mbuf);
    gemm_mfma_kernel<0><<<gb, 256, 0, stream>>>(mbuf, xb, whi + 0 * 256 * FF, bl0, hA);
    // layer 1: m = mean(h1); h2 = relu(m@Wl1 + h1@Wr1 + bl1)  (writes hB = xb buffer)
    aggregate_kernel<<<ab, 256, 0, stream>>>(hA, rowptr, col, mbuf);
    gemm_mfma_kernel<0><<<gb, 256, 0, stream>>>(mbuf, hA, whi + 1 * 256 * FF, bl1, hB);
    // layer 2: m = mean(h2); out = m@Wl2 + h2@Wr2 + bl2  (fp32, no relu)
    aggregate_kernel<<<ab, 256, 0, stream>>>(hB, rowptr, col, mbuf);
    gemm_mfma_kernel<1><<<gb, 256, 0, stream>>>(mbuf, hB, whi + 2 * 256 * FF, bl2, out);
}